// Round 1
// baseline (437.257 us; speedup 1.0000x reference)
//
#include <hip/hip_runtime.h>
#include <hip/hip_bf16.h>

// FractalAttention on MI355X.
// Math: per level k, out = reshape-scatter( (x viewed [8192,1024]) @ Mcat_k + b ),
// where Mcat_k[j*128+d, h*128+e] = sum_d' W[k,h,d,d'] * w_mix[j*128+d', e].
// Precision: A and B kept as bf16 hi/lo planes; 3-term MFMA (AhBh+AhBl+AlBh) ~ fp32.

typedef __attribute__((ext_vector_type(8))) __bf16 bf16x8;
typedef __attribute__((ext_vector_type(4))) float f32x4;
typedef __attribute__((ext_vector_type(4))) unsigned short us4;

#define DEVI static __device__ __forceinline__

DEVI unsigned short f2bf(float f) {
  unsigned u = __builtin_bit_cast(unsigned, f);
  unsigned r = (u + 0x7fffu + ((u >> 16) & 1u)) >> 16;
  return (unsigned short)r;
}
DEVI float bf2f(unsigned short s) {
  return __builtin_bit_cast(float, (unsigned)s << 16);
}

DEVI void gload_lds16(const void* g, void* l) {
  __builtin_amdgcn_global_load_lds(
      (const __attribute__((address_space(1))) void*)g,
      (__attribute__((address_space(3))) void*)l,
      16, 0, 0);
}

// ---------------------------------------------------------------------------
// Precompute MT[lvl][h*128+e][j*128+d] = sum_d2 W[lvl,h,d,d2]*wmix[j*128+d2,e]
// stored transposed (N-major rows, K columns) as bf16 hi/lo planes.
// grid = 256 (lvl*64 + h*8 + j), block = 256.
// ---------------------------------------------------------------------------
__global__ __launch_bounds__(256) void precompute_MT(
    const float* __restrict__ W, const float* __restrict__ wmix,
    unsigned short* __restrict__ MTh, unsigned short* __restrict__ MTl)
{
  __shared__ float sW[128 * 128];  // W[lvl][h][d][d2]
  __shared__ float sV[128 * 128];  // wmix[j*128+d2][e]
  const int wg = blockIdx.x;
  const int lvl = wg >> 6, h = (wg >> 3) & 7, j = wg & 7;
  const float* Wp = W + (size_t)(lvl * 8 + h) * 128 * 128;
  const float* Vp = wmix + (size_t)(j * 128) * 128;
  const int tid = threadIdx.x;
  for (int i = tid; i < 128 * 128 / 4; i += 256) {
    ((float4*)sW)[i] = ((const float4*)Wp)[i];
    ((float4*)sV)[i] = ((const float4*)Vp)[i];
  }
  __syncthreads();
  const int e = tid >> 1;
  const int d0 = (tid & 1) * 64;
  float acc[64];
#pragma unroll
  for (int t = 0; t < 64; ++t) acc[t] = 0.f;
  for (int d2 = 0; d2 < 128; d2 += 4) {
    const float v0 = sV[(d2 + 0) * 128 + e];
    const float v1 = sV[(d2 + 1) * 128 + e];
    const float v2 = sV[(d2 + 2) * 128 + e];
    const float v3 = sV[(d2 + 3) * 128 + e];
#pragma unroll 16
    for (int t = 0; t < 64; ++t) {
      const float4 wv = *(const float4*)&sW[(d0 + t) * 128 + d2];
      acc[t] += wv.x * v0 + wv.y * v1 + wv.z * v2 + wv.w * v3;
    }
  }
  const size_t rowbase =
      ((size_t)lvl * 1024 + h * 128 + e) * 1024 + j * 128 + d0;
#pragma unroll 16
  for (int t = 0; t < 64; ++t) {
    const float m = acc[t];
    const unsigned short hb = f2bf(m);
    MTh[rowbase + t] = hb;
    MTl[rowbase + t] = f2bf(m - bf2f(hb));
  }
}

// ---------------------------------------------------------------------------
// fp32 -> bf16 hi/lo planes
// ---------------------------------------------------------------------------
__global__ __launch_bounds__(256) void split_kernel(
    const float* __restrict__ x, unsigned short* __restrict__ hi,
    unsigned short* __restrict__ lo, int n4)
{
  const int stride = gridDim.x * 256;
  for (int i = blockIdx.x * 256 + threadIdx.x; i < n4; i += stride) {
    const float4 v = ((const float4*)x)[i];
    float vv[4] = {v.x, v.y, v.z, v.w};
    us4 hv, lv;
#pragma unroll
    for (int t = 0; t < 4; ++t) {
      const unsigned short hb = f2bf(vv[t]);
      hv[t] = hb;
      lv[t] = f2bf(vv[t] - bf2f(hb));
    }
    ((us4*)hi)[i] = hv;
    ((us4*)lo)[i] = lv;
  }
}

// ---------------------------------------------------------------------------
// Level GEMM: C[8192,1024] = A[8192,1024] @ Mcat[1024,1024] + bias, with the
// per-(coltile h) output row remap. 128x128 tile, BK=64, 4 waves (2x2),
// 16x16x32 bf16 MFMA, 3-term hi/lo. OUT_MODE 0: bf16 hi/lo planes; 1: fp32.
// grid = (8 coltiles, 64 rowtiles), block = 256.
// ---------------------------------------------------------------------------
template <int OUT_MODE>
__global__ __launch_bounds__(256, 2) void level_gemm(
    const unsigned short* __restrict__ Ah, const unsigned short* __restrict__ Al,
    const unsigned short* __restrict__ Bh, const unsigned short* __restrict__ Bl,
    const float* __restrict__ bias, unsigned short* __restrict__ Oh,
    unsigned short* __restrict__ Ol, float* __restrict__ Ofp, int lshift)
{
  __shared__ unsigned short sAh[128 * 64];
  __shared__ unsigned short sAl[128 * 64];
  __shared__ unsigned short sBh[128 * 64];  // stored [col][k] (Mcat^T rows)
  __shared__ unsigned short sBl[128 * 64];

  const int tid = threadIdx.x;
  const int h = blockIdx.x;
  const int g0 = blockIdx.y * 128;

  const int w = tid >> 6, lane = tid & 63;
  // staging: each wave moves 1KB per issue; 4 issues cover a 128x64 bf16 tile
  const int srow = w * 8 + (lane >> 3);
  const int scol = (lane & 7) * 8;
  const size_t aoff = (size_t)(g0 + srow) * 1024 + scol;
  const size_t boff = (size_t)(h * 128 + srow) * 1024 + scol;
  const int ldst = w * 512;  // wave-uniform LDS element base (+ lane*8 implicit)

  f32x4 acc[4][4] = {};

  const int wm = w >> 1, wn = w & 1;

  for (int kb = 0; kb < 16; ++kb) {
    const int kc = kb * 64;
#pragma unroll
    for (int i = 0; i < 4; ++i) {
      const size_t go = (size_t)i * 32 * 1024 + kc;
      const int lo_ = ldst + i * 2048;
      gload_lds16(Ah + aoff + go, sAh + lo_);
      gload_lds16(Al + aoff + go, sAl + lo_);
      gload_lds16(Bh + boff + go, sBh + lo_);
      gload_lds16(Bl + boff + go, sBl + lo_);
    }
    __syncthreads();
#pragma unroll
    for (int kk = 0; kk < 2; ++kk) {
      bf16x8 fah[4], fal[4], fbh[4], fbl[4];
      const int ko = kk * 32 + ((lane >> 4) << 3);
#pragma unroll
      for (int m = 0; m < 4; ++m) {
        const int row = wm * 64 + m * 16 + (lane & 15);
        fah[m] = *(const bf16x8*)(sAh + row * 64 + ko);
        fal[m] = *(const bf16x8*)(sAl + row * 64 + ko);
      }
#pragma unroll
      for (int n = 0; n < 4; ++n) {
        const int col = wn * 64 + n * 16 + (lane & 15);
        fbh[n] = *(const bf16x8*)(sBh + col * 64 + ko);
        fbl[n] = *(const bf16x8*)(sBl + col * 64 + ko);
      }
#pragma unroll
      for (int m = 0; m < 4; ++m) {
#pragma unroll
        for (int n = 0; n < 4; ++n) {
          acc[m][n] = __builtin_amdgcn_mfma_f32_16x16x32_bf16(
              fah[m], fbh[n], acc[m][n], 0, 0, 0);
          acc[m][n] = __builtin_amdgcn_mfma_f32_16x16x32_bf16(
              fah[m], fbl[n], acc[m][n], 0, 0, 0);
          acc[m][n] = __builtin_amdgcn_mfma_f32_16x16x32_bf16(
              fal[m], fbh[n], acc[m][n], 0, 0, 0);
        }
      }
    }
    __syncthreads();
  }

  // Epilogue: out global row = b*8192 + n*L + h*(L/8) + r ; contiguous block.
  const int bss = lshift - 3;              // log2(L/8)
  const int q = g0 & 1023;
  const int n_idx = q >> bss;
  const int r0 = q & ((1 << bss) - 1);
  const long srow0 = (long)(g0 >> 10) * 8192 + ((long)n_idx << lshift) +
                     ((long)h << bss) + r0;
  const size_t obase = (size_t)srow0 * 128;

#pragma unroll
  for (int m = 0; m < 4; ++m) {
#pragma unroll
    for (int n = 0; n < 4; ++n) {
      const int col = wn * 64 + n * 16 + (lane & 15);
      const float bv = bias[col];
#pragma unroll
      for (int i = 0; i < 4; ++i) {
        const int row = wm * 64 + m * 16 + ((lane >> 4) << 2) + i;
        const float v = acc[m][n][i] + bv;
        const size_t p = obase + (size_t)row * 128 + col;
        if (OUT_MODE) {
          Ofp[p] = v;
        } else {
          const unsigned short hb = f2bf(v);
          Oh[p] = hb;
          Ol[p] = f2bf(v - bf2f(hb));
        }
      }
    }
  }
}

// ---------------------------------------------------------------------------
extern "C" void kernel_launch(void* const* d_in, const int* in_sizes, int n_in,
                              void* d_out, int out_size, void* d_ws,
                              size_t ws_size, hipStream_t stream) {
  const float* x = (const float*)d_in[0];
  const float* W = (const float*)d_in[1];    // [4,8,128,128]
  const float* wmx = (const float*)d_in[2];  // [1024,128]
  const float* bmx = (const float*)d_in[3];  // [128]
  float* out = (float*)d_out;

  const size_t NELEM = 8ull * 8192 * 128;  // 8388608
  const size_t MTSZ = 4ull * 1024 * 1024;  // elems per MT plane

  unsigned short* MTh = (unsigned short*)d_ws;
  unsigned short* MTl = MTh + MTSZ;
  unsigned short* Xh_ws = MTl + MTSZ;
  unsigned short* Xl_ws = Xh_ws + NELEM;
  // d_out (32MB) doubles as the second hi/lo plane pair between levels
  unsigned short* Xh_do = (unsigned short*)d_out;
  unsigned short* Xl_do = Xh_do + NELEM;

  precompute_MT<<<dim3(256), dim3(256), 0, stream>>>(W, wmx, MTh, MTl);
  split_kernel<<<dim3(2048), dim3(256), 0, stream>>>(x, Xh_do, Xl_do,
                                                     (int)(NELEM / 4));

  dim3 grid(8, 64), blk(256);
  // Level 1: L=1024
  level_gemm<0><<<grid, blk, 0, stream>>>(Xh_do, Xl_do, MTh + 0 * 1048576ull,
                                          MTl + 0 * 1048576ull, bmx, Xh_ws,
                                          Xl_ws, nullptr, 10);
  // Level 2: L=2048
  level_gemm<0><<<grid, blk, 0, stream>>>(Xh_ws, Xl_ws, MTh + 1 * 1048576ull,
                                          MTl + 1 * 1048576ull, bmx, Xh_do,
                                          Xl_do, nullptr, 11);
  // Level 3: L=4096
  level_gemm<0><<<grid, blk, 0, stream>>>(Xh_do, Xl_do, MTh + 2 * 1048576ull,
                                          MTl + 2 * 1048576ull, bmx, Xh_ws,
                                          Xl_ws, nullptr, 12);
  // Level 4: L=8192 -> fp32 out
  level_gemm<1><<<grid, blk, 0, stream>>>(Xh_ws, Xl_ws, MTh + 3 * 1048576ull,
                                          MTl + 3 * 1048576ull, bmx, nullptr,
                                          nullptr, out, 13);
}

// Round 2
// 351.763 us; speedup vs baseline: 1.2430x; 1.2430x over previous
//
#include <hip/hip_runtime.h>
#include <hip/hip_bf16.h>

// FractalAttention on MI355X.
// Math: per level k, out = reshape-scatter( (x viewed [8192,1024]) @ Mcat_k + b ),
// where Mcat_k[j*128+d, h*128+e] = sum_d' W[k,h,d,d'] * w_mix[j*128+d', e].
// Precision: A and B kept as bf16 hi/lo planes; 3-term MFMA (AhBh+AhBl+AlBh) ~ fp32.

typedef __attribute__((ext_vector_type(8))) __bf16 bf16x8;
typedef __attribute__((ext_vector_type(4))) float f32x4;
typedef __attribute__((ext_vector_type(4))) unsigned short us4;
typedef __attribute__((ext_vector_type(8))) unsigned short us8;

#define DEVI static __device__ __forceinline__

DEVI unsigned short f2bf(float f) {
  unsigned u = __builtin_bit_cast(unsigned, f);
  unsigned r = (u + 0x7fffu + ((u >> 16) & 1u)) >> 16;
  return (unsigned short)r;
}
DEVI float bf2f(unsigned short s) {
  return __builtin_bit_cast(float, (unsigned)s << 16);
}

DEVI void gload_lds16(const void* g, void* l) {
  __builtin_amdgcn_global_load_lds(
      (const __attribute__((address_space(1))) void*)g,
      (__attribute__((address_space(3))) void*)l,
      16, 0, 0);
}

// ---------------------------------------------------------------------------
// Precompute MT[lvl][h*128+e][j*128+d] = sum_d2 W[lvl,h,d,d2]*wmix[j*128+d2,e]
// (N-major rows, K columns) as bf16 hi/lo planes.
// No LDS: W-block walk has ~8KB L1 working set; wmix rows broadcast.
// grid = 1024 (lvl,h,j,e-quarter), block = 256; thread owns 2(e) x 8(d) tile.
// Stores: us8 (16B) per row per plane; lanes 0-15 cover d=0..127 contiguously.
// ---------------------------------------------------------------------------
__global__ __launch_bounds__(256) void precompute_MT(
    const float* __restrict__ W, const float* __restrict__ wmix,
    unsigned short* __restrict__ MTh, unsigned short* __restrict__ MTl)
{
  const int wg = blockIdx.x;
  const int q = wg & 3;           // e-quarter
  const int j = (wg >> 2) & 7;
  const int h = (wg >> 5) & 7;
  const int lvl = wg >> 8;
  const int tid = threadIdx.x;
  const int e0 = q * 32 + (tid >> 4) * 2;  // 2 consecutive e rows
  const int d0 = (tid & 15) * 8;           // 8 consecutive d cols

  const float* Wrow = W + (size_t)(lvl * 8 + h) * 16384 + (size_t)d0 * 128;
  const float* Vcol = wmix + (size_t)j * 16384 + e0;  // row stride 128

  float acc[2][8];
#pragma unroll
  for (int er = 0; er < 2; ++er)
#pragma unroll
    for (int r = 0; r < 8; ++r) acc[er][r] = 0.f;

  for (int d2 = 0; d2 < 128; d2 += 4) {
    float4 wv[8];
#pragma unroll
    for (int r = 0; r < 8; ++r)
      wv[r] = *(const float4*)(Wrow + r * 128 + d2);
    float2 mv[4];
#pragma unroll
    for (int c = 0; c < 4; ++c)
      mv[c] = *(const float2*)(Vcol + (size_t)(d2 + c) * 128);
#pragma unroll
    for (int r = 0; r < 8; ++r) {
      acc[0][r] += wv[r].x * mv[0].x + wv[r].y * mv[1].x +
                   wv[r].z * mv[2].x + wv[r].w * mv[3].x;
      acc[1][r] += wv[r].x * mv[0].y + wv[r].y * mv[1].y +
                   wv[r].z * mv[2].y + wv[r].w * mv[3].y;
    }
  }

#pragma unroll
  for (int er = 0; er < 2; ++er) {
    const size_t base = (size_t)lvl * 1048576 +
                        (size_t)(h * 128 + e0 + er) * 1024 + j * 128 + d0;
    us8 hv, lv;
#pragma unroll
    for (int r = 0; r < 8; ++r) {
      const float m = acc[er][r];
      const unsigned short hb = f2bf(m);
      hv[r] = hb;
      lv[r] = f2bf(m - bf2f(hb));
    }
    *(us8*)(MTh + base) = hv;
    *(us8*)(MTl + base) = lv;
  }
}

// ---------------------------------------------------------------------------
// fp32 -> bf16 hi/lo planes
// ---------------------------------------------------------------------------
__global__ __launch_bounds__(256) void split_kernel(
    const float* __restrict__ x, unsigned short* __restrict__ hi,
    unsigned short* __restrict__ lo, int n4)
{
  const int stride = gridDim.x * 256;
  for (int i = blockIdx.x * 256 + threadIdx.x; i < n4; i += stride) {
    const float4 v = ((const float4*)x)[i];
    float vv[4] = {v.x, v.y, v.z, v.w};
    us4 hv, lv;
#pragma unroll
    for (int t = 0; t < 4; ++t) {
      const unsigned short hb = f2bf(vv[t]);
      hv[t] = hb;
      lv[t] = f2bf(vv[t] - bf2f(hb));
    }
    ((us4*)hi)[i] = hv;
    ((us4*)lo)[i] = lv;
  }
}

// ---------------------------------------------------------------------------
// Level GEMM: C[8192,1024] = A[8192,1024] @ Mcat[1024,1024] + bias, with the
// per-(coltile h) output row remap. 128x128 tile, BK=64, 4 waves (2x2),
// 16x16x32 bf16 MFMA, 3-term hi/lo. OUT_MODE 0: bf16 hi/lo planes; 1: fp32.
// grid = (8 coltiles, 64 rowtiles), block = 256.
// ---------------------------------------------------------------------------
template <int OUT_MODE>
__global__ __launch_bounds__(256, 2) void level_gemm(
    const unsigned short* __restrict__ Ah, const unsigned short* __restrict__ Al,
    const unsigned short* __restrict__ Bh, const unsigned short* __restrict__ Bl,
    const float* __restrict__ bias, unsigned short* __restrict__ Oh,
    unsigned short* __restrict__ Ol, float* __restrict__ Ofp, int lshift)
{
  __shared__ unsigned short sAh[128 * 64];
  __shared__ unsigned short sAl[128 * 64];
  __shared__ unsigned short sBh[128 * 64];  // stored [col][k] (Mcat^T rows)
  __shared__ unsigned short sBl[128 * 64];

  const int tid = threadIdx.x;
  const int h = blockIdx.x;
  const int g0 = blockIdx.y * 128;

  const int w = tid >> 6, lane = tid & 63;
  // staging: each wave moves 1KB per issue; 4 issues cover a 128x64 bf16 tile
  const int srow = w * 8 + (lane >> 3);
  const int scol = (lane & 7) * 8;
  const size_t aoff = (size_t)(g0 + srow) * 1024 + scol;
  const size_t boff = (size_t)(h * 128 + srow) * 1024 + scol;
  const int ldst = w * 512;  // wave-uniform LDS element base (+ lane*8 implicit)

  f32x4 acc[4][4] = {};

  const int wm = w >> 1, wn = w & 1;

  for (int kb = 0; kb < 16; ++kb) {
    const int kc = kb * 64;
#pragma unroll
    for (int i = 0; i < 4; ++i) {
      const size_t go = (size_t)i * 32 * 1024 + kc;
      const int lo_ = ldst + i * 2048;
      gload_lds16(Ah + aoff + go, sAh + lo_);
      gload_lds16(Al + aoff + go, sAl + lo_);
      gload_lds16(Bh + boff + go, sBh + lo_);
      gload_lds16(Bl + boff + go, sBl + lo_);
    }
    __syncthreads();
#pragma unroll
    for (int kk = 0; kk < 2; ++kk) {
      bf16x8 fah[4], fal[4], fbh[4], fbl[4];
      const int ko = kk * 32 + ((lane >> 4) << 3);
#pragma unroll
      for (int m = 0; m < 4; ++m) {
        const int row = wm * 64 + m * 16 + (lane & 15);
        fah[m] = *(const bf16x8*)(sAh + row * 64 + ko);
        fal[m] = *(const bf16x8*)(sAl + row * 64 + ko);
      }
#pragma unroll
      for (int n = 0; n < 4; ++n) {
        const int col = wn * 64 + n * 16 + (lane & 15);
        fbh[n] = *(const bf16x8*)(sBh + col * 64 + ko);
        fbl[n] = *(const bf16x8*)(sBl + col * 64 + ko);
      }
#pragma unroll
      for (int m = 0; m < 4; ++m) {
#pragma unroll
        for (int n = 0; n < 4; ++n) {
          acc[m][n] = __builtin_amdgcn_mfma_f32_16x16x32_bf16(
              fah[m], fbh[n], acc[m][n], 0, 0, 0);
          acc[m][n] = __builtin_amdgcn_mfma_f32_16x16x32_bf16(
              fah[m], fbl[n], acc[m][n], 0, 0, 0);
          acc[m][n] = __builtin_amdgcn_mfma_f32_16x16x32_bf16(
              fal[m], fbh[n], acc[m][n], 0, 0, 0);
        }
      }
    }
    __syncthreads();
  }

  // Epilogue: out global row = b*8192 + n*L + h*(L/8) + r ; contiguous block.
  const int bss = lshift - 3;              // log2(L/8)
  const int q = g0 & 1023;
  const int n_idx = q >> bss;
  const int r0 = q & ((1 << bss) - 1);
  const long srow0 = (long)(g0 >> 10) * 8192 + ((long)n_idx << lshift) +
                     ((long)h << bss) + r0;
  const size_t obase = (size_t)srow0 * 128;

#pragma unroll
  for (int m = 0; m < 4; ++m) {
#pragma unroll
    for (int n = 0; n < 4; ++n) {
      const int col = wn * 64 + n * 16 + (lane & 15);
      const float bv = bias[col];
#pragma unroll
      for (int i = 0; i < 4; ++i) {
        const int row = wm * 64 + m * 16 + ((lane >> 4) << 2) + i;
        const float v = acc[m][n][i] + bv;
        const size_t p = obase + (size_t)row * 128 + col;
        if (OUT_MODE) {
          Ofp[p] = v;
        } else {
          const unsigned short hb = f2bf(v);
          Oh[p] = hb;
          Ol[p] = f2bf(v - bf2f(hb));
        }
      }
    }
  }
}

// ---------------------------------------------------------------------------
extern "C" void kernel_launch(void* const* d_in, const int* in_sizes, int n_in,
                              void* d_out, int out_size, void* d_ws,
                              size_t ws_size, hipStream_t stream) {
  const float* x = (const float*)d_in[0];
  const float* W = (const float*)d_in[1];    // [4,8,128,128]
  const float* wmx = (const float*)d_in[2];  // [1024,128]
  const float* bmx = (const float*)d_in[3];  // [128]
  float* out = (float*)d_out;

  const size_t NELEM = 8ull * 8192 * 128;  // 8388608
  const size_t MTSZ = 4ull * 1024 * 1024;  // elems per MT plane

  unsigned short* MTh = (unsigned short*)d_ws;
  unsigned short* MTl = MTh + MTSZ;
  unsigned short* Xh_ws = MTl + MTSZ;
  unsigned short* Xl_ws = Xh_ws + NELEM;
  // d_out (32MB) doubles as the second hi/lo plane pair between levels
  unsigned short* Xh_do = (unsigned short*)d_out;
  unsigned short* Xl_do = Xh_do + NELEM;

  precompute_MT<<<dim3(1024), dim3(256), 0, stream>>>(W, wmx, MTh, MTl);
  split_kernel<<<dim3(2048), dim3(256), 0, stream>>>(x, Xh_do, Xl_do,
                                                     (int)(NELEM / 4));

  dim3 grid(8, 64), blk(256);
  // Level 1: L=1024
  level_gemm<0><<<grid, blk, 0, stream>>>(Xh_do, Xl_do, MTh + 0 * 1048576ull,
                                          MTl + 0 * 1048576ull, bmx, Xh_ws,
                                          Xl_ws, nullptr, 10);
  // Level 2: L=2048
  level_gemm<0><<<grid, blk, 0, stream>>>(Xh_ws, Xl_ws, MTh + 1 * 1048576ull,
                                          MTl + 1 * 1048576ull, bmx, Xh_do,
                                          Xl_do, nullptr, 11);
  // Level 3: L=4096
  level_gemm<0><<<grid, blk, 0, stream>>>(Xh_do, Xl_do, MTh + 2 * 1048576ull,
                                          MTl + 2 * 1048576ull, bmx, Xh_ws,
                                          Xl_ws, nullptr, 12);
  // Level 4: L=8192 -> fp32 out
  level_gemm<1><<<grid, blk, 0, stream>>>(Xh_ws, Xl_ws, MTh + 3 * 1048576ull,
                                          MTl + 3 * 1048576ull, bmx, nullptr,
                                          nullptr, out, 13);
}

// Round 3
// 243.666 us; speedup vs baseline: 1.7945x; 1.4436x over previous
//
#include <hip/hip_runtime.h>
#include <hip/hip_bf16.h>

// FractalAttention on MI355X.
// Math: per level k, out = reshape-scatter( (x viewed [8192,1024]) @ Mcat_k + b ),
// where Mcat_k[j*128+d, h*128+e] = sum_d' W[k,h,d,d'] * w_mix[j*128+d', e].
// Precision: bf16 hi/lo planes everywhere; 3-term MFMA (AhBh+AhBl+AlBh) ~ fp32.
// Mcat itself is computed by MFMA: MT_block[e][d] = wmixT_j[e][d2] . W[d][d2].

typedef __attribute__((ext_vector_type(8))) __bf16 bf16x8;
typedef __attribute__((ext_vector_type(4))) float f32x4;
typedef __attribute__((ext_vector_type(4))) unsigned short us4;
typedef __attribute__((ext_vector_type(8))) unsigned short us8;

#define DEVI static __device__ __forceinline__

DEVI unsigned short f2bf(float f) {
  unsigned u = __builtin_bit_cast(unsigned, f);
  unsigned r = (u + 0x7fffu + ((u >> 16) & 1u)) >> 16;
  return (unsigned short)r;
}
DEVI float bf2f(unsigned short s) {
  return __builtin_bit_cast(float, (unsigned)s << 16);
}

DEVI void gload_lds16(const void* g, void* l) {
  __builtin_amdgcn_global_load_lds(
      (const __attribute__((address_space(1))) void*)g,
      (__attribute__((address_space(3))) void*)l,
      16, 0, 0);
}

// ---------------------------------------------------------------------------
// fp32 -> bf16 hi/lo planes (used for x and for W)
// ---------------------------------------------------------------------------
__global__ __launch_bounds__(256) void split_kernel(
    const float* __restrict__ x, unsigned short* __restrict__ hi,
    unsigned short* __restrict__ lo, int n4)
{
  const int stride = gridDim.x * 256;
  for (int i = blockIdx.x * 256 + threadIdx.x; i < n4; i += stride) {
    const float4 v = ((const float4*)x)[i];
    float vv[4] = {v.x, v.y, v.z, v.w};
    us4 hv, lv;
#pragma unroll
    for (int t = 0; t < 4; ++t) {
      const unsigned short hb = f2bf(vv[t]);
      hv[t] = hb;
      lv[t] = f2bf(vv[t] - bf2f(hb));
    }
    ((us4*)hi)[i] = hv;
    ((us4*)lo)[i] = lv;
  }
}

// ---------------------------------------------------------------------------
// wmix [1024(j*128+d2)][128(e)] fp32 -> wmixT [128(e)][1024(j*128+d2)]
// bf16 hi/lo planes. grid = 8 (j), block = 256. LDS transpose, padded.
// ---------------------------------------------------------------------------
__global__ __launch_bounds__(256) void wmixT_split(
    const float* __restrict__ wmix, unsigned short* __restrict__ Th,
    unsigned short* __restrict__ Tl)
{
  __shared__ float sT[128][129];
  const int j = blockIdx.x;
  const int tid = threadIdx.x;
  const float* src = wmix + (size_t)j * 16384;
  for (int i = tid; i < 16384 / 4; i += 256) {
    const int d2 = i >> 5;
    const int e4 = (i & 31) * 4;
    const float4 v = *(const float4*)(src + d2 * 128 + e4);
    sT[e4 + 0][d2] = v.x;
    sT[e4 + 1][d2] = v.y;
    sT[e4 + 2][d2] = v.z;
    sT[e4 + 3][d2] = v.w;
  }
  __syncthreads();
  const int e = tid >> 1;
  const int d2h = (tid & 1) * 64;
  const size_t base = (size_t)e * 1024 + j * 128 + d2h;
#pragma unroll
  for (int r = 0; r < 8; ++r) {
    us8 hv, lv;
#pragma unroll
    for (int t = 0; t < 8; ++t) {
      const float m = sT[e][d2h + r * 8 + t];
      const unsigned short hb = f2bf(m);
      hv[t] = hb;
      lv[t] = f2bf(m - bf2f(hb));
    }
    *(us8*)(Th + base + r * 8) = hv;
    *(us8*)(Tl + base + r * 8) = lv;
  }
}

// ---------------------------------------------------------------------------
// MFMA precompute: for (lvl,h,j): MT[lvlh*131072 + e*1024 + j*128 + d]
//   = sum_d2 wmixT[e][j*128+d2] * W[lvlh][d][d2]   (3-term hi/lo)
// grid = (8 j, 32 lvlh), block = 256 (4 waves, 2x2), K=128 in 2 steps of 64.
// ---------------------------------------------------------------------------
__global__ __launch_bounds__(256, 2) void precompute_MT_mfma(
    const unsigned short* __restrict__ Ah, const unsigned short* __restrict__ Al,
    const unsigned short* __restrict__ Bh, const unsigned short* __restrict__ Bl,
    unsigned short* __restrict__ MTh, unsigned short* __restrict__ MTl)
{
  __shared__ unsigned short sAh[128 * 64];
  __shared__ unsigned short sAl[128 * 64];
  __shared__ unsigned short sBh[128 * 64];
  __shared__ unsigned short sBl[128 * 64];

  const int tid = threadIdx.x;
  const int j = blockIdx.x;
  const int lvlh = blockIdx.y;

  const int w = tid >> 6, lane = tid & 63;
  const int srow = w * 8 + (lane >> 3);
  const int scol = (lane & 7) * 8;
  // A rows (e): wmixT row stride 1024
  const size_t aoff = (size_t)srow * 1024 + j * 128 + scol;
  // B rows (d): W row stride 128
  const size_t boff = (size_t)lvlh * 16384 + (size_t)srow * 128 + scol;
  const int ldst = w * 512;

  f32x4 acc[4][4] = {};
  const int wm = w >> 1, wn = w & 1;

  for (int kb = 0; kb < 2; ++kb) {
    const int kc = kb * 64;
#pragma unroll
    for (int i = 0; i < 4; ++i) {
      const int lo_ = ldst + i * 2048;
      gload_lds16(Ah + aoff + (size_t)i * 32 * 1024 + kc, sAh + lo_);
      gload_lds16(Al + aoff + (size_t)i * 32 * 1024 + kc, sAl + lo_);
      gload_lds16(Bh + boff + (size_t)i * 32 * 128 + kc, sBh + lo_);
      gload_lds16(Bl + boff + (size_t)i * 32 * 128 + kc, sBl + lo_);
    }
    __syncthreads();
#pragma unroll
    for (int kk = 0; kk < 2; ++kk) {
      bf16x8 fah[4], fal[4], fbh[4], fbl[4];
      const int ko = kk * 32 + ((lane >> 4) << 3);
#pragma unroll
      for (int m = 0; m < 4; ++m) {
        const int row = wm * 64 + m * 16 + (lane & 15);
        fah[m] = *(const bf16x8*)(sAh + row * 64 + ko);
        fal[m] = *(const bf16x8*)(sAl + row * 64 + ko);
      }
#pragma unroll
      for (int n = 0; n < 4; ++n) {
        const int col = wn * 64 + n * 16 + (lane & 15);
        fbh[n] = *(const bf16x8*)(sBh + col * 64 + ko);
        fbl[n] = *(const bf16x8*)(sBl + col * 64 + ko);
      }
#pragma unroll
      for (int m = 0; m < 4; ++m) {
#pragma unroll
        for (int n = 0; n < 4; ++n) {
          acc[m][n] = __builtin_amdgcn_mfma_f32_16x16x32_bf16(
              fah[m], fbh[n], acc[m][n], 0, 0, 0);
          acc[m][n] = __builtin_amdgcn_mfma_f32_16x16x32_bf16(
              fah[m], fbl[n], acc[m][n], 0, 0, 0);
          acc[m][n] = __builtin_amdgcn_mfma_f32_16x16x32_bf16(
              fal[m], fbh[n], acc[m][n], 0, 0, 0);
        }
      }
    }
    __syncthreads();
  }

  // C[e][d] -> MT[lvlh*131072 + e*1024 + j*128 + d], hi/lo split
  const size_t mtbase = (size_t)lvlh * 131072 + (size_t)j * 128;
#pragma unroll
  for (int m = 0; m < 4; ++m) {
#pragma unroll
    for (int n = 0; n < 4; ++n) {
      const int d = wn * 64 + n * 16 + (lane & 15);
#pragma unroll
      for (int i = 0; i < 4; ++i) {
        const int e = wm * 64 + m * 16 + ((lane >> 4) << 2) + i;
        const float v = acc[m][n][i];
        const size_t p = mtbase + (size_t)e * 1024 + d;
        const unsigned short hb = f2bf(v);
        MTh[p] = hb;
        MTl[p] = f2bf(v - bf2f(hb));
      }
    }
  }
}

// ---------------------------------------------------------------------------
// Level GEMM: C[8192,1024] = A[8192,1024] @ Mcat[1024,1024] + bias, with the
// per-(coltile h) output row remap. 128x128 tile, BK=64, 4 waves (2x2),
// 16x16x32 bf16 MFMA, 3-term hi/lo. OUT_MODE 0: bf16 hi/lo planes; 1: fp32.
// grid = (8 coltiles, 64 rowtiles), block = 256.
// ---------------------------------------------------------------------------
template <int OUT_MODE>
__global__ __launch_bounds__(256, 2) void level_gemm(
    const unsigned short* __restrict__ Ah, const unsigned short* __restrict__ Al,
    const unsigned short* __restrict__ Bh, const unsigned short* __restrict__ Bl,
    const float* __restrict__ bias, unsigned short* __restrict__ Oh,
    unsigned short* __restrict__ Ol, float* __restrict__ Ofp, int lshift)
{
  __shared__ unsigned short sAh[128 * 64];
  __shared__ unsigned short sAl[128 * 64];
  __shared__ unsigned short sBh[128 * 64];  // stored [col][k] (Mcat^T rows)
  __shared__ unsigned short sBl[128 * 64];

  const int tid = threadIdx.x;
  const int h = blockIdx.x;
  const int g0 = blockIdx.y * 128;

  const int w = tid >> 6, lane = tid & 63;
  const int srow = w * 8 + (lane >> 3);
  const int scol = (lane & 7) * 8;
  const size_t aoff = (size_t)(g0 + srow) * 1024 + scol;
  const size_t boff = (size_t)(h * 128 + srow) * 1024 + scol;
  const int ldst = w * 512;

  f32x4 acc[4][4] = {};
  const int wm = w >> 1, wn = w & 1;

  for (int kb = 0; kb < 16; ++kb) {
    const int kc = kb * 64;
#pragma unroll
    for (int i = 0; i < 4; ++i) {
      const size_t go = (size_t)i * 32 * 1024 + kc;
      const int lo_ = ldst + i * 2048;
      gload_lds16(Ah + aoff + go, sAh + lo_);
      gload_lds16(Al + aoff + go, sAl + lo_);
      gload_lds16(Bh + boff + go, sBh + lo_);
      gload_lds16(Bl + boff + go, sBl + lo_);
    }
    __syncthreads();
#pragma unroll
    for (int kk = 0; kk < 2; ++kk) {
      bf16x8 fah[4], fal[4], fbh[4], fbl[4];
      const int ko = kk * 32 + ((lane >> 4) << 3);
#pragma unroll
      for (int m = 0; m < 4; ++m) {
        const int row = wm * 64 + m * 16 + (lane & 15);
        fah[m] = *(const bf16x8*)(sAh + row * 64 + ko);
        fal[m] = *(const bf16x8*)(sAl + row * 64 + ko);
      }
#pragma unroll
      for (int n = 0; n < 4; ++n) {
        const int col = wn * 64 + n * 16 + (lane & 15);
        fbh[n] = *(const bf16x8*)(sBh + col * 64 + ko);
        fbl[n] = *(const bf16x8*)(sBl + col * 64 + ko);
      }
#pragma unroll
      for (int m = 0; m < 4; ++m) {
#pragma unroll
        for (int n = 0; n < 4; ++n) {
          acc[m][n] = __builtin_amdgcn_mfma_f32_16x16x32_bf16(
              fah[m], fbh[n], acc[m][n], 0, 0, 0);
          acc[m][n] = __builtin_amdgcn_mfma_f32_16x16x32_bf16(
              fah[m], fbl[n], acc[m][n], 0, 0, 0);
          acc[m][n] = __builtin_amdgcn_mfma_f32_16x16x32_bf16(
              fal[m], fbh[n], acc[m][n], 0, 0, 0);
        }
      }
    }
    __syncthreads();
  }

  // Epilogue: out global row = b*8192 + n*L + h*(L/8) + r ; contiguous block.
  const int bss = lshift - 3;              // log2(L/8)
  const int q = g0 & 1023;
  const int n_idx = q >> bss;
  const int r0 = q & ((1 << bss) - 1);
  const long srow0 = (long)(g0 >> 10) * 8192 + ((long)n_idx << lshift) +
                     ((long)h << bss) + r0;
  const size_t obase = (size_t)srow0 * 128;

#pragma unroll
  for (int m = 0; m < 4; ++m) {
#pragma unroll
    for (int n = 0; n < 4; ++n) {
      const int col = wn * 64 + n * 16 + (lane & 15);
      const float bv = bias[col];
#pragma unroll
      for (int i = 0; i < 4; ++i) {
        const int row = wm * 64 + m * 16 + ((lane >> 4) << 2) + i;
        const float v = acc[m][n][i] + bv;
        const size_t p = obase + (size_t)row * 128 + col;
        if (OUT_MODE) {
          Ofp[p] = v;
        } else {
          const unsigned short hb = f2bf(v);
          Oh[p] = hb;
          Ol[p] = f2bf(v - bf2f(hb));
        }
      }
    }
  }
}

// ---------------------------------------------------------------------------
extern "C" void kernel_launch(void* const* d_in, const int* in_sizes, int n_in,
                              void* d_out, int out_size, void* d_ws,
                              size_t ws_size, hipStream_t stream) {
  const float* x = (const float*)d_in[0];
  const float* W = (const float*)d_in[1];    // [4,8,128,128]
  const float* wmx = (const float*)d_in[2];  // [1024,128]
  const float* bmx = (const float*)d_in[3];  // [128]
  float* out = (float*)d_out;

  const size_t NELEM = 8ull * 8192 * 128;   // 8388608
  const size_t MTSZ = 4ull * 1024 * 1024;   // elems per MT plane
  const size_t WSZ = 4ull * 8 * 128 * 128;  // 524288 W elems
  const size_t WTSZ = 128ull * 1024;        // 131072 wmixT elems

  unsigned short* MTh = (unsigned short*)d_ws;
  unsigned short* MTl = MTh + MTSZ;
  unsigned short* Xh_ws = MTl + MTSZ;
  unsigned short* Xl_ws = Xh_ws + NELEM;
  unsigned short* Wh = Xl_ws + NELEM;
  unsigned short* Wl = Wh + WSZ;
  unsigned short* wTh = Wl + WSZ;
  unsigned short* wTl = wTh + WTSZ;
  // d_out (32MB) doubles as the second hi/lo plane pair between levels
  unsigned short* Xh_do = (unsigned short*)d_out;
  unsigned short* Xl_do = Xh_do + NELEM;

  split_kernel<<<dim3(2048), dim3(256), 0, stream>>>(x, Xh_do, Xl_do,
                                                     (int)(NELEM / 4));
  split_kernel<<<dim3(512), dim3(256), 0, stream>>>(W, Wh, Wl,
                                                    (int)(WSZ / 4));
  wmixT_split<<<dim3(8), dim3(256), 0, stream>>>(wmx, wTh, wTl);
  precompute_MT_mfma<<<dim3(8, 32), dim3(256), 0, stream>>>(wTh, wTl, Wh, Wl,
                                                            MTh, MTl);

  dim3 grid(8, 64), blk(256);
  // Level 1: L=1024
  level_gemm<0><<<grid, blk, 0, stream>>>(Xh_do, Xl_do, MTh + 0 * 1048576ull,
                                          MTl + 0 * 1048576ull, bmx, Xh_ws,
                                          Xl_ws, nullptr, 10);
  // Level 2: L=2048
  level_gemm<0><<<grid, blk, 0, stream>>>(Xh_ws, Xl_ws, MTh + 1 * 1048576ull,
                                          MTl + 1 * 1048576ull, bmx, Xh_do,
                                          Xl_do, nullptr, 11);
  // Level 3: L=4096
  level_gemm<0><<<grid, blk, 0, stream>>>(Xh_do, Xl_do, MTh + 2 * 1048576ull,
                                          MTl + 2 * 1048576ull, bmx, Xh_ws,
                                          Xl_ws, nullptr, 12);
  // Level 4: L=8192 -> fp32 out
  level_gemm<1><<<grid, blk, 0, stream>>>(Xh_ws, Xl_ws, MTh + 3 * 1048576ull,
                                          MTl + 3 * 1048576ull, bmx, nullptr,
                                          nullptr, out, 13);
}

// Round 4
// 144.142 us; speedup vs baseline: 3.0335x; 1.6905x over previous
//
#include <hip/hip_runtime.h>
#include <hip/hip_bf16.h>

// FractalAttention on MI355X.
// Math: per level k, out = reshape-scatter( (x viewed [8192,1024]) @ Mcat_k + b ),
// where Mcat_k[j*128+d, h*128+e] = sum_d' W[k,h,d,d'] * w_mix[j*128+d', e].
// Precision: Mcat computed via 3-term bf16 hi/lo MFMA (near-fp32), stored fp16.
// Levels run single-plane fp16 MFMA (error ~1e-3 rel, far under 2% threshold).

typedef __attribute__((ext_vector_type(8))) __bf16 bf16x8;
typedef __attribute__((ext_vector_type(8))) _Float16 half8;
typedef __attribute__((ext_vector_type(4))) float f32x4;
typedef __attribute__((ext_vector_type(4))) unsigned short us4;
typedef __attribute__((ext_vector_type(8))) unsigned short us8;

#define DEVI static __device__ __forceinline__

DEVI unsigned short f2bf(float f) {
  unsigned u = __builtin_bit_cast(unsigned, f);
  unsigned r = (u + 0x7fffu + ((u >> 16) & 1u)) >> 16;
  return (unsigned short)r;
}
DEVI float bf2f(unsigned short s) {
  return __builtin_bit_cast(float, (unsigned)s << 16);
}
DEVI unsigned short f2h(float f) {
  return __builtin_bit_cast(unsigned short, (_Float16)f);
}

DEVI void gload_lds16(const void* g, void* l) {
  __builtin_amdgcn_global_load_lds(
      (const __attribute__((address_space(1))) void*)g,
      (__attribute__((address_space(3))) void*)l,
      16, 0, 0);
}

// ---------------------------------------------------------------------------
// fp32 -> bf16 hi/lo planes (used for W; feeds the high-precision precompute)
// ---------------------------------------------------------------------------
__global__ __launch_bounds__(256) void split_kernel(
    const float* __restrict__ x, unsigned short* __restrict__ hi,
    unsigned short* __restrict__ lo, int n4)
{
  const int stride = gridDim.x * 256;
  for (int i = blockIdx.x * 256 + threadIdx.x; i < n4; i += stride) {
    const float4 v = ((const float4*)x)[i];
    float vv[4] = {v.x, v.y, v.z, v.w};
    us4 hv, lv;
#pragma unroll
    for (int t = 0; t < 4; ++t) {
      const unsigned short hb = f2bf(vv[t]);
      hv[t] = hb;
      lv[t] = f2bf(vv[t] - bf2f(hb));
    }
    ((us4*)hi)[i] = hv;
    ((us4*)lo)[i] = lv;
  }
}

// ---------------------------------------------------------------------------
// fp32 -> fp16 single plane (x input)
// ---------------------------------------------------------------------------
__global__ __launch_bounds__(256) void split_f16(
    const float* __restrict__ x, unsigned short* __restrict__ o, int n4)
{
  const int stride = gridDim.x * 256;
  for (int i = blockIdx.x * 256 + threadIdx.x; i < n4; i += stride) {
    const float4 v = ((const float4*)x)[i];
    us4 hv;
    hv[0] = f2h(v.x);
    hv[1] = f2h(v.y);
    hv[2] = f2h(v.z);
    hv[3] = f2h(v.w);
    ((us4*)o)[i] = hv;
  }
}

// ---------------------------------------------------------------------------
// wmix [1024(j*128+d2)][128(e)] fp32 -> wmixT [128(e)][1024(j*128+d2)]
// bf16 hi/lo planes. grid = 8 (j), block = 256. LDS transpose, padded.
// ---------------------------------------------------------------------------
__global__ __launch_bounds__(256) void wmixT_split(
    const float* __restrict__ wmix, unsigned short* __restrict__ Th,
    unsigned short* __restrict__ Tl)
{
  __shared__ float sT[128][129];
  const int j = blockIdx.x;
  const int tid = threadIdx.x;
  const float* src = wmix + (size_t)j * 16384;
  for (int i = tid; i < 16384 / 4; i += 256) {
    const int d2 = i >> 5;
    const int e4 = (i & 31) * 4;
    const float4 v = *(const float4*)(src + d2 * 128 + e4);
    sT[e4 + 0][d2] = v.x;
    sT[e4 + 1][d2] = v.y;
    sT[e4 + 2][d2] = v.z;
    sT[e4 + 3][d2] = v.w;
  }
  __syncthreads();
  const int e = tid >> 1;
  const int d2h = (tid & 1) * 64;
  const size_t base = (size_t)e * 1024 + j * 128 + d2h;
#pragma unroll
  for (int r = 0; r < 8; ++r) {
    us8 hv, lv;
#pragma unroll
    for (int t = 0; t < 8; ++t) {
      const float m = sT[e][d2h + r * 8 + t];
      const unsigned short hb = f2bf(m);
      hv[t] = hb;
      lv[t] = f2bf(m - bf2f(hb));
    }
    *(us8*)(Th + base + r * 8) = hv;
    *(us8*)(Tl + base + r * 8) = lv;
  }
}

// ---------------------------------------------------------------------------
// MFMA precompute: for (lvl,h,j): MT16[lvlh*131072 + e*1024 + j*128 + d]
//   = sum_d2 wmixT[e][j*128+d2] * W[lvlh][d][d2]   (3-term hi/lo, fp16 out)
// grid = (8 j, 32 lvlh), block = 256 (4 waves, 2x2), K=128 in 2 steps of 64.
// ---------------------------------------------------------------------------
__global__ __launch_bounds__(256, 2) void precompute_MT_mfma(
    const unsigned short* __restrict__ Ah, const unsigned short* __restrict__ Al,
    const unsigned short* __restrict__ Bh, const unsigned short* __restrict__ Bl,
    unsigned short* __restrict__ MT16)
{
  __shared__ unsigned short sAh[128 * 64];
  __shared__ unsigned short sAl[128 * 64];
  __shared__ unsigned short sBh[128 * 64];
  __shared__ unsigned short sBl[128 * 64];

  const int tid = threadIdx.x;
  const int j = blockIdx.x;
  const int lvlh = blockIdx.y;

  const int w = tid >> 6, lane = tid & 63;
  const int srow = w * 8 + (lane >> 3);
  const int scol = (lane & 7) * 8;
  // A rows (e): wmixT row stride 1024
  const size_t aoff = (size_t)srow * 1024 + j * 128 + scol;
  // B rows (d): W row stride 128
  const size_t boff = (size_t)lvlh * 16384 + (size_t)srow * 128 + scol;
  const int ldst = w * 512;

  f32x4 acc[4][4] = {};
  const int wm = w >> 1, wn = w & 1;

  for (int kb = 0; kb < 2; ++kb) {
    const int kc = kb * 64;
#pragma unroll
    for (int i = 0; i < 4; ++i) {
      const int lo_ = ldst + i * 2048;
      gload_lds16(Ah + aoff + (size_t)i * 32 * 1024 + kc, sAh + lo_);
      gload_lds16(Al + aoff + (size_t)i * 32 * 1024 + kc, sAl + lo_);
      gload_lds16(Bh + boff + (size_t)i * 32 * 128 + kc, sBh + lo_);
      gload_lds16(Bl + boff + (size_t)i * 32 * 128 + kc, sBl + lo_);
    }
    __syncthreads();
#pragma unroll
    for (int kk = 0; kk < 2; ++kk) {
      bf16x8 fah[4], fal[4], fbh[4], fbl[4];
      const int ko = kk * 32 + ((lane >> 4) << 3);
#pragma unroll
      for (int m = 0; m < 4; ++m) {
        const int row = wm * 64 + m * 16 + (lane & 15);
        fah[m] = *(const bf16x8*)(sAh + row * 64 + ko);
        fal[m] = *(const bf16x8*)(sAl + row * 64 + ko);
      }
#pragma unroll
      for (int n = 0; n < 4; ++n) {
        const int col = wn * 64 + n * 16 + (lane & 15);
        fbh[n] = *(const bf16x8*)(sBh + col * 64 + ko);
        fbl[n] = *(const bf16x8*)(sBl + col * 64 + ko);
      }
#pragma unroll
      for (int m = 0; m < 4; ++m) {
#pragma unroll
        for (int n = 0; n < 4; ++n) {
          acc[m][n] = __builtin_amdgcn_mfma_f32_16x16x32_bf16(
              fah[m], fbh[n], acc[m][n], 0, 0, 0);
          acc[m][n] = __builtin_amdgcn_mfma_f32_16x16x32_bf16(
              fah[m], fbl[n], acc[m][n], 0, 0, 0);
          acc[m][n] = __builtin_amdgcn_mfma_f32_16x16x32_bf16(
              fal[m], fbh[n], acc[m][n], 0, 0, 0);
        }
      }
    }
    __syncthreads();
  }

  // C[e][d] -> MT16[lvlh*131072 + e*1024 + j*128 + d], fp16
  const size_t mtbase = (size_t)lvlh * 131072 + (size_t)j * 128;
#pragma unroll
  for (int m = 0; m < 4; ++m) {
#pragma unroll
    for (int n = 0; n < 4; ++n) {
      const int d = wn * 64 + n * 16 + (lane & 15);
#pragma unroll
      for (int i = 0; i < 4; ++i) {
        const int e = wm * 64 + m * 16 + ((lane >> 4) << 2) + i;
        MT16[mtbase + (size_t)e * 1024 + d] = f2h(acc[m][n][i]);
      }
    }
  }
}

// ---------------------------------------------------------------------------
// Level GEMM (fp16, single-term): C[8192,1024] = A @ Mcat + bias, with the
// per-(coltile h) output row remap. 128x128 tile, BK=64, 4 waves (2x2),
// 16x16x32 f16 MFMA. OUT_MODE 0: fp16 plane; 1: fp32.
// grid = (64 rowtiles, 8 coltiles) -> id%8 XCD round-robin groups row%8,
// keeping each XCD's A strips + all of B ~4MB (L2-resident).
// ---------------------------------------------------------------------------
template <int OUT_MODE>
__global__ __launch_bounds__(256, 4) void level_gemm_f16(
    const unsigned short* __restrict__ A, const unsigned short* __restrict__ B,
    const float* __restrict__ bias, unsigned short* __restrict__ O16,
    float* __restrict__ Ofp, int lshift)
{
  __shared__ unsigned short sA[128 * 64];
  __shared__ unsigned short sB[128 * 64];  // stored [col][k] (Mcat^T rows)

  const int tid = threadIdx.x;
  const int h = blockIdx.y;
  const int g0 = blockIdx.x * 128;

  const int w = tid >> 6, lane = tid & 63;
  const int srow = w * 8 + (lane >> 3);
  const int scol = (lane & 7) * 8;
  const size_t aoff = (size_t)(g0 + srow) * 1024 + scol;
  const size_t boff = (size_t)(h * 128 + srow) * 1024 + scol;
  const int ldst = w * 512;

  f32x4 acc[4][4] = {};
  const int wm = w >> 1, wn = w & 1;

  for (int kb = 0; kb < 16; ++kb) {
    const int kc = kb * 64;
#pragma unroll
    for (int i = 0; i < 4; ++i) {
      const size_t go = (size_t)i * 32 * 1024 + kc;
      const int lo_ = ldst + i * 2048;
      gload_lds16(A + aoff + go, sA + lo_);
      gload_lds16(B + boff + go, sB + lo_);
    }
    __syncthreads();
#pragma unroll
    for (int kk = 0; kk < 2; ++kk) {
      half8 fa[4], fb[4];
      const int ko = kk * 32 + ((lane >> 4) << 3);
#pragma unroll
      for (int m = 0; m < 4; ++m) {
        const int row = wm * 64 + m * 16 + (lane & 15);
        fa[m] = *(const half8*)(sA + row * 64 + ko);
      }
#pragma unroll
      for (int n = 0; n < 4; ++n) {
        const int col = wn * 64 + n * 16 + (lane & 15);
        fb[n] = *(const half8*)(sB + col * 64 + ko);
      }
#pragma unroll
      for (int m = 0; m < 4; ++m) {
#pragma unroll
        for (int n = 0; n < 4; ++n) {
          acc[m][n] = __builtin_amdgcn_mfma_f32_16x16x32_f16(
              fa[m], fb[n], acc[m][n], 0, 0, 0);
        }
      }
    }
    __syncthreads();
  }

  // Epilogue: out global row = b*8192 + n*L + h*(L/8) + r ; contiguous block.
  const int bss = lshift - 3;              // log2(L/8)
  const int q = g0 & 1023;
  const int n_idx = q >> bss;
  const int r0 = q & ((1 << bss) - 1);
  const long srow0 = (long)(g0 >> 10) * 8192 + ((long)n_idx << lshift) +
                     ((long)h << bss) + r0;
  const size_t obase = (size_t)srow0 * 128;

#pragma unroll
  for (int m = 0; m < 4; ++m) {
#pragma unroll
    for (int n = 0; n < 4; ++n) {
      const int col = wn * 64 + n * 16 + (lane & 15);
      const float bv = bias[col];
#pragma unroll
      for (int i = 0; i < 4; ++i) {
        const int row = wm * 64 + m * 16 + ((lane >> 4) << 2) + i;
        const float v = acc[m][n][i] + bv;
        const size_t p = obase + (size_t)row * 128 + col;
        if (OUT_MODE) {
          Ofp[p] = v;
        } else {
          O16[p] = f2h(v);
        }
      }
    }
  }
}

// ---------------------------------------------------------------------------
extern "C" void kernel_launch(void* const* d_in, const int* in_sizes, int n_in,
                              void* d_out, int out_size, void* d_ws,
                              size_t ws_size, hipStream_t stream) {
  const float* x = (const float*)d_in[0];
  const float* W = (const float*)d_in[1];    // [4,8,128,128]
  const float* wmx = (const float*)d_in[2];  // [1024,128]
  const float* bmx = (const float*)d_in[3];  // [128]
  float* out = (float*)d_out;

  const size_t NELEM = 8ull * 8192 * 128;   // 8388608
  const size_t MTSZ = 4ull * 1024 * 1024;   // 4194304 MT16 elems
  const size_t WSZ = 4ull * 8 * 128 * 128;  // 524288 W elems
  const size_t WTSZ = 128ull * 1024;        // 131072 wmixT elems

  // ws layout (ushort elems): MT16 | Wh | Wl | wTh | wTl | Xa | Xc
  unsigned short* MT16 = (unsigned short*)d_ws;
  unsigned short* Wh = MT16 + MTSZ;
  unsigned short* Wl = Wh + WSZ;
  unsigned short* wTh = Wl + WSZ;
  unsigned short* wTl = wTh + WTSZ;
  unsigned short* Xa = wTl + WTSZ;   // 16 MB
  unsigned short* Xc = Xa + NELEM;   // 16 MB
  // d_out lower half doubles as the level-1 output plane
  unsigned short* Xb = (unsigned short*)d_out;

  split_kernel<<<dim3(512), dim3(256), 0, stream>>>(W, Wh, Wl, (int)(WSZ / 4));
  wmixT_split<<<dim3(8), dim3(256), 0, stream>>>(wmx, wTh, wTl);
  precompute_MT_mfma<<<dim3(8, 32), dim3(256), 0, stream>>>(wTh, wTl, Wh, Wl,
                                                            MT16);
  split_f16<<<dim3(2048), dim3(256), 0, stream>>>(x, Xa, (int)(NELEM / 4));

  dim3 grid(64, 8), blk(256);
  // Level 1 (L=1024): Xa -> Xb (d_out lower half)
  level_gemm_f16<0><<<grid, blk, 0, stream>>>(Xa, MT16 + 0 * 1048576ull, bmx,
                                              Xb, nullptr, 10);
  // Level 2 (L=2048): Xb -> Xc
  level_gemm_f16<0><<<grid, blk, 0, stream>>>(Xb, MT16 + 1 * 1048576ull, bmx,
                                              Xc, nullptr, 11);
  // Level 3 (L=4096): Xc -> Xa
  level_gemm_f16<0><<<grid, blk, 0, stream>>>(Xc, MT16 + 2 * 1048576ull, bmx,
                                              Xa, nullptr, 12);
  // Level 4 (L=8192): Xa -> fp32 out (full d_out overwrite)
  level_gemm_f16<1><<<grid, blk, 0, stream>>>(Xa, MT16 + 3 * 1048576ull, bmx,
                                              nullptr, out, 13);
}

// Round 5
// 119.050 us; speedup vs baseline: 3.6729x; 1.2108x over previous
//
#include <hip/hip_runtime.h>
#include <hip/hip_bf16.h>

// FractalAttention on MI355X.
// Math: per level k, out = reshape-scatter( (x viewed [8192,1024]) @ Mcat_k + b ),
// where Mcat_k[j*128+d, h*128+e] = sum_d' W[k,h,d,d'] * w_mix[j*128+d', e].
// Precision: Mcat computed via 3-term bf16 hi/lo MFMA (near-fp32), stored fp16.
// Levels run single-plane fp16 MFMA. Level GEMM uses 2-phase double-buffered
// LDS with counted vmcnt (T4) + XOR bank swizzle (T2, both-sides involution).

typedef __attribute__((ext_vector_type(8))) __bf16 bf16x8;
typedef __attribute__((ext_vector_type(8))) _Float16 half8;
typedef __attribute__((ext_vector_type(4))) float f32x4;
typedef __attribute__((ext_vector_type(4))) unsigned short us4;
typedef __attribute__((ext_vector_type(8))) unsigned short us8;

#define DEVI static __device__ __forceinline__

DEVI unsigned short f2bf(float f) {
  unsigned u = __builtin_bit_cast(unsigned, f);
  unsigned r = (u + 0x7fffu + ((u >> 16) & 1u)) >> 16;
  return (unsigned short)r;
}
DEVI float bf2f(unsigned short s) {
  return __builtin_bit_cast(float, (unsigned)s << 16);
}
DEVI unsigned short f2h(float f) {
  return __builtin_bit_cast(unsigned short, (_Float16)f);
}

DEVI void gload_lds16(const void* g, void* l) {
  __builtin_amdgcn_global_load_lds(
      (const __attribute__((address_space(1))) void*)g,
      (__attribute__((address_space(3))) void*)l,
      16, 0, 0);
}

// ---------------------------------------------------------------------------
// fp32 -> bf16 hi/lo planes (used for W; feeds the high-precision precompute)
// ---------------------------------------------------------------------------
__global__ __launch_bounds__(256) void split_kernel(
    const float* __restrict__ x, unsigned short* __restrict__ hi,
    unsigned short* __restrict__ lo, int n4)
{
  const int stride = gridDim.x * 256;
  for (int i = blockIdx.x * 256 + threadIdx.x; i < n4; i += stride) {
    const float4 v = ((const float4*)x)[i];
    float vv[4] = {v.x, v.y, v.z, v.w};
    us4 hv, lv;
#pragma unroll
    for (int t = 0; t < 4; ++t) {
      const unsigned short hb = f2bf(vv[t]);
      hv[t] = hb;
      lv[t] = f2bf(vv[t] - bf2f(hb));
    }
    ((us4*)hi)[i] = hv;
    ((us4*)lo)[i] = lv;
  }
}

// ---------------------------------------------------------------------------
// fp32 -> fp16 single plane (x input)
// ---------------------------------------------------------------------------
__global__ __launch_bounds__(256) void split_f16(
    const float* __restrict__ x, unsigned short* __restrict__ o, int n4)
{
  const int stride = gridDim.x * 256;
  for (int i = blockIdx.x * 256 + threadIdx.x; i < n4; i += stride) {
    const float4 v = ((const float4*)x)[i];
    us4 hv;
    hv[0] = f2h(v.x);
    hv[1] = f2h(v.y);
    hv[2] = f2h(v.z);
    hv[3] = f2h(v.w);
    ((us4*)o)[i] = hv;
  }
}

// ---------------------------------------------------------------------------
// wmix [1024(j*128+d2)][128(e)] fp32 -> wmixT [128(e)][1024(j*128+d2)]
// bf16 hi/lo planes. grid = 8 (j), block = 256. LDS transpose, padded.
// ---------------------------------------------------------------------------
__global__ __launch_bounds__(256) void wmixT_split(
    const float* __restrict__ wmix, unsigned short* __restrict__ Th,
    unsigned short* __restrict__ Tl)
{
  __shared__ float sT[128][129];
  const int j = blockIdx.x;
  const int tid = threadIdx.x;
  const float* src = wmix + (size_t)j * 16384;
  for (int i = tid; i < 16384 / 4; i += 256) {
    const int d2 = i >> 5;
    const int e4 = (i & 31) * 4;
    const float4 v = *(const float4*)(src + d2 * 128 + e4);
    sT[e4 + 0][d2] = v.x;
    sT[e4 + 1][d2] = v.y;
    sT[e4 + 2][d2] = v.z;
    sT[e4 + 3][d2] = v.w;
  }
  __syncthreads();
  const int e = tid >> 1;
  const int d2h = (tid & 1) * 64;
  const size_t base = (size_t)e * 1024 + j * 128 + d2h;
#pragma unroll
  for (int r = 0; r < 8; ++r) {
    us8 hv, lv;
#pragma unroll
    for (int t = 0; t < 8; ++t) {
      const float m = sT[e][d2h + r * 8 + t];
      const unsigned short hb = f2bf(m);
      hv[t] = hb;
      lv[t] = f2bf(m - bf2f(hb));
    }
    *(us8*)(Th + base + r * 8) = hv;
    *(us8*)(Tl + base + r * 8) = lv;
  }
}

// ---------------------------------------------------------------------------
// MFMA precompute: for (lvl,h,j): MT16[lvlh*131072 + e*1024 + j*128 + d]
//   = sum_d2 wmixT[e][j*128+d2] * W[lvlh][d][d2]   (3-term hi/lo, fp16 out)
// grid = (8 j, 32 lvlh), block = 256 (4 waves, 2x2), K=128 in 2 steps of 64.
// ---------------------------------------------------------------------------
__global__ __launch_bounds__(256, 2) void precompute_MT_mfma(
    const unsigned short* __restrict__ Ah, const unsigned short* __restrict__ Al,
    const unsigned short* __restrict__ Bh, const unsigned short* __restrict__ Bl,
    unsigned short* __restrict__ MT16)
{
  __shared__ unsigned short sAh[128 * 64];
  __shared__ unsigned short sAl[128 * 64];
  __shared__ unsigned short sBh[128 * 64];
  __shared__ unsigned short sBl[128 * 64];

  const int tid = threadIdx.x;
  const int j = blockIdx.x;
  const int lvlh = blockIdx.y;

  const int w = tid >> 6, lane = tid & 63;
  const int srow = w * 8 + (lane >> 3);
  const int scol = (lane & 7) * 8;
  // A rows (e): wmixT row stride 1024
  const size_t aoff = (size_t)srow * 1024 + j * 128 + scol;
  // B rows (d): W row stride 128
  const size_t boff = (size_t)lvlh * 16384 + (size_t)srow * 128 + scol;
  const int ldst = w * 512;

  f32x4 acc[4][4] = {};
  const int wm = w >> 1, wn = w & 1;

  for (int kb = 0; kb < 2; ++kb) {
    const int kc = kb * 64;
#pragma unroll
    for (int i = 0; i < 4; ++i) {
      const int lo_ = ldst + i * 2048;
      gload_lds16(Ah + aoff + (size_t)i * 32 * 1024 + kc, sAh + lo_);
      gload_lds16(Al + aoff + (size_t)i * 32 * 1024 + kc, sAl + lo_);
      gload_lds16(Bh + boff + (size_t)i * 32 * 128 + kc, sBh + lo_);
      gload_lds16(Bl + boff + (size_t)i * 32 * 128 + kc, sBl + lo_);
    }
    __syncthreads();
#pragma unroll
    for (int kk = 0; kk < 2; ++kk) {
      bf16x8 fah[4], fal[4], fbh[4], fbl[4];
      const int ko = kk * 32 + ((lane >> 4) << 3);
#pragma unroll
      for (int m = 0; m < 4; ++m) {
        const int row = wm * 64 + m * 16 + (lane & 15);
        fah[m] = *(const bf16x8*)(sAh + row * 64 + ko);
        fal[m] = *(const bf16x8*)(sAl + row * 64 + ko);
      }
#pragma unroll
      for (int n = 0; n < 4; ++n) {
        const int col = wn * 64 + n * 16 + (lane & 15);
        fbh[n] = *(const bf16x8*)(sBh + col * 64 + ko);
        fbl[n] = *(const bf16x8*)(sBl + col * 64 + ko);
      }
#pragma unroll
      for (int m = 0; m < 4; ++m) {
#pragma unroll
        for (int n = 0; n < 4; ++n) {
          acc[m][n] = __builtin_amdgcn_mfma_f32_16x16x32_bf16(
              fah[m], fbh[n], acc[m][n], 0, 0, 0);
          acc[m][n] = __builtin_amdgcn_mfma_f32_16x16x32_bf16(
              fah[m], fbl[n], acc[m][n], 0, 0, 0);
          acc[m][n] = __builtin_amdgcn_mfma_f32_16x16x32_bf16(
              fal[m], fbh[n], acc[m][n], 0, 0, 0);
        }
      }
    }
    __syncthreads();
  }

  // C[e][d] -> MT16[lvlh*131072 + e*1024 + j*128 + d], fp16
  const size_t mtbase = (size_t)lvlh * 131072 + (size_t)j * 128;
#pragma unroll
  for (int m = 0; m < 4; ++m) {
#pragma unroll
    for (int n = 0; n < 4; ++n) {
      const int d = wn * 64 + n * 16 + (lane & 15);
#pragma unroll
      for (int i = 0; i < 4; ++i) {
        const int e = wm * 64 + m * 16 + ((lane >> 4) << 2) + i;
        MT16[mtbase + (size_t)e * 1024 + d] = f2h(acc[m][n][i]);
      }
    }
  }
}

// ---------------------------------------------------------------------------
// Level GEMM (fp16): C[8192,1024] = A @ Mcat + bias, with the per-(coltile h)
// output row remap. 128x128 tile, BK=64, 4 waves (2x2), 16x16x32 f16 MFMA.
// 2-phase double-buffered LDS with counted vmcnt(8); XOR bank swizzle:
//   LDS slot s of row r holds global 16B-slot s^(r&7); read ko ^= (row&7)<<3.
// OUT_MODE 0: fp16 plane; 1: fp32.
// grid = (64 rowtiles, 8 coltiles) -> id%8 XCD round-robin groups row%8.
// ---------------------------------------------------------------------------
template <int OUT_MODE>
__global__ __launch_bounds__(256, 2) void level_gemm_f16(
    const unsigned short* __restrict__ A, const unsigned short* __restrict__ B,
    const float* __restrict__ bias, unsigned short* __restrict__ O16,
    float* __restrict__ Ofp, int lshift)
{
  __shared__ unsigned short sA[2][128 * 64];
  __shared__ unsigned short sB[2][128 * 64];

  const int tid = threadIdx.x;
  const int h = blockIdx.y;
  const int g0 = blockIdx.x * 128;

  const int w = tid >> 6, lane = tid & 63;
  const int srow = w * 8 + (lane >> 3);
  // inverse-swizzled global source column: LDS stays linear (gload_lds),
  // so lane (writing LDS slot lane&7 of row srow) fetches global slot
  // (lane&7)^(srow&7); srow&7 == lane>>3 for every issue i and wave w.
  const int xcol = ((lane & 7) ^ (lane >> 3)) * 8;
  const size_t aoff = (size_t)(g0 + srow) * 1024 + xcol;
  const size_t boff = (size_t)(h * 128 + srow) * 1024 + xcol;
  const int ldst = w * 512;

  f32x4 acc[4][4] = {};
  const int wm = w >> 1, wn = w & 1;

#define STAGE_LG(buf, kc_)                                                  \
  {                                                                         \
    _Pragma("unroll") for (int i_ = 0; i_ < 4; ++i_) {                      \
      const size_t go_ = (size_t)i_ * 32 * 1024 + (size_t)(kc_);            \
      const int lo_ = ldst + i_ * 2048;                                     \
      gload_lds16(A + aoff + go_, sA[buf] + lo_);                           \
      gload_lds16(B + boff + go_, sB[buf] + lo_);                           \
    }                                                                       \
  }

  STAGE_LG(0, 0);
  int cur = 0;
  for (int kb = 0; kb < 16; ++kb) {
    if (kb < 15) {
      STAGE_LG(cur ^ 1, (kb + 1) * 64);
      asm volatile("s_waitcnt vmcnt(8)" ::: "memory");
    } else {
      asm volatile("s_waitcnt vmcnt(0)" ::: "memory");
    }
    __builtin_amdgcn_sched_barrier(0);
    __builtin_amdgcn_s_barrier();
    __builtin_amdgcn_sched_barrier(0);
    const unsigned short* sAc = sA[cur];
    const unsigned short* sBc = sB[cur];
#pragma unroll
    for (int kk = 0; kk < 2; ++kk) {
      half8 fa[4], fb[4];
      const int ko = (kk * 32 + ((lane >> 4) << 3)) ^ ((lane & 7) << 3);
#pragma unroll
      for (int m = 0; m < 4; ++m) {
        const int row = wm * 64 + m * 16 + (lane & 15);
        fa[m] = *(const half8*)(sAc + row * 64 + ko);
      }
#pragma unroll
      for (int n = 0; n < 4; ++n) {
        const int col = wn * 64 + n * 16 + (lane & 15);
        fb[n] = *(const half8*)(sBc + col * 64 + ko);
      }
#pragma unroll
      for (int m = 0; m < 4; ++m) {
#pragma unroll
        for (int n = 0; n < 4; ++n) {
          acc[m][n] = __builtin_amdgcn_mfma_f32_16x16x32_f16(
              fa[m], fb[n], acc[m][n], 0, 0, 0);
        }
      }
    }
    __builtin_amdgcn_sched_barrier(0);
    __builtin_amdgcn_s_barrier();
    __builtin_amdgcn_sched_barrier(0);
    cur ^= 1;
  }
#undef STAGE_LG

  // Epilogue: out global row = b*8192 + n*L + h*(L/8) + r ; contiguous block.
  const int bss = lshift - 3;              // log2(L/8)
  const int q = g0 & 1023;
  const int n_idx = q >> bss;
  const int r0 = q & ((1 << bss) - 1);
  const long srow0 = (long)(g0 >> 10) * 8192 + ((long)n_idx << lshift) +
                     ((long)h << bss) + r0;
  const size_t obase = (size_t)srow0 * 128;

#pragma unroll
  for (int m = 0; m < 4; ++m) {
#pragma unroll
    for (int n = 0; n < 4; ++n) {
      const int col = wn * 64 + n * 16 + (lane & 15);
      const float bv = bias[col];
#pragma unroll
      for (int i = 0; i < 4; ++i) {
        const int row = wm * 64 + m * 16 + ((lane >> 4) << 2) + i;
        const float v = acc[m][n][i] + bv;
        const size_t p = obase + (size_t)row * 128 + col;
        if (OUT_MODE) {
          Ofp[p] = v;
        } else {
          O16[p] = f2h(v);
        }
      }
    }
  }
}

// ---------------------------------------------------------------------------
extern "C" void kernel_launch(void* const* d_in, const int* in_sizes, int n_in,
                              void* d_out, int out_size, void* d_ws,
                              size_t ws_size, hipStream_t stream) {
  const float* x = (const float*)d_in[0];
  const float* W = (const float*)d_in[1];    // [4,8,128,128]
  const float* wmx = (const float*)d_in[2];  // [1024,128]
  const float* bmx = (const float*)d_in[3];  // [128]
  float* out = (float*)d_out;

  const size_t NELEM = 8ull * 8192 * 128;   // 8388608
  const size_t MTSZ = 4ull * 1024 * 1024;   // 4194304 MT16 elems
  const size_t WSZ = 4ull * 8 * 128 * 128;  // 524288 W elems
  const size_t WTSZ = 128ull * 1024;        // 131072 wmixT elems

  // ws layout (ushort elems): MT16 | Wh | Wl | wTh | wTl | Xa | Xc
  unsigned short* MT16 = (unsigned short*)d_ws;
  unsigned short* Wh = MT16 + MTSZ;
  unsigned short* Wl = Wh + WSZ;
  unsigned short* wTh = Wl + WSZ;
  unsigned short* wTl = wTh + WTSZ;
  unsigned short* Xa = wTl + WTSZ;   // 16 MB
  unsigned short* Xc = Xa + NELEM;   // 16 MB
  // d_out lower half doubles as the level-1 output plane
  unsigned short* Xb = (unsigned short*)d_out;

  split_kernel<<<dim3(512), dim3(256), 0, stream>>>(W, Wh, Wl, (int)(WSZ / 4));
  wmixT_split<<<dim3(8), dim3(256), 0, stream>>>(wmx, wTh, wTl);
  precompute_MT_mfma<<<dim3(8, 32), dim3(256), 0, stream>>>(wTh, wTl, Wh, Wl,
                                                            MT16);
  split_f16<<<dim3(2048), dim3(256), 0, stream>>>(x, Xa, (int)(NELEM / 4));

  dim3 grid(64, 8), blk(256);
  // Level 1 (L=1024): Xa -> Xb (d_out lower half)
  level_gemm_f16<0><<<grid, blk, 0, stream>>>(Xa, MT16 + 0 * 1048576ull, bmx,
                                              Xb, nullptr, 10);
  // Level 2 (L=2048): Xb -> Xc
  level_gemm_f16<0><<<grid, blk, 0, stream>>>(Xb, MT16 + 1 * 1048576ull, bmx,
                                              Xc, nullptr, 11);
  // Level 3 (L=4096): Xc -> Xa
  level_gemm_f16<0><<<grid, blk, 0, stream>>>(Xc, MT16 + 2 * 1048576ull, bmx,
                                              Xa, nullptr, 12);
  // Level 4 (L=8192): Xa -> fp32 out (full d_out overwrite)
  level_gemm_f16<1><<<grid, blk, 0, stream>>>(Xa, MT16 + 3 * 1048576ull, bmx,
                                              nullptr, out, 13);
}